// Round 1
// baseline (1045.530 us; speedup 1.0000x reference)
//
#include <hip/hip_runtime.h>
#include <hip/hip_bf16.h>
#include <math.h>

// Problem constants (from reference)
#define T_    4096
#define B_    32
#define F_    3
#define L_    4
#define D_    64
#define DI_   128
#define DS_   16
#define DTR_  4
#define KC_   4
#define NXP_  36        // DTR + 2*DS
#define EPS_  1e-6f

// Chunking
#define CH_   128             // SSM / mid-pipeline chunk length
#define NC_   (T_/CH_)        // 32 chunks
#define CHE_  64              // EMA chunk length
#define NCE_  (T_/CHE_)       // 64 chunks

// ---------------- workspace layout (float offsets) ----------------
#define XE_OFF    ((size_t)0)                          // T*B*12
#define H_OFF     (XE_OFF   + (size_t)T_*B_*12)        // T*B*64
#define XC_OFF    (H_OFF    + (size_t)T_*B_*64)        // T*B*128 (silu'd)
#define SRES_OFF  (XC_OFF   + (size_t)T_*B_*128)       // T*B*128 (silu'd res)
#define XP_OFF    (SRES_OFF + (size_t)T_*B_*128)       // T*B*36
#define HEND_OFF  (XP_OFF   + (size_t)T_*B_*36)        // NC*B*DI*DS
#define SUMD_OFF  (HEND_OFF + (size_t)NC_*B_*DI_*DS_)  // NC*B*DI
#define HST_OFF   (SUMD_OFF + (size_t)NC_*B_*DI_)      // NC*B*DI*DS
#define EME_OFF   (HST_OFF  + (size_t)NC_*B_*DI_*DS_)  // NCE*B*F*L
#define EVE_OFF   (EME_OFF  + (size_t)NCE_*B_*F_*L_)
#define EMS_OFF   (EVE_OFF  + (size_t)NCE_*B_*F_*L_)
#define EVS_OFF   (EMS_OFF  + (size_t)NCE_*B_*F_*L_)
// total ~52.7M floats ~211 MB

__device__ __forceinline__ float sigmoidf_(float x) { return 1.f / (1.f + __expf(-x)); }
__device__ __forceinline__ float softplusf_(float x) {
    return fmaxf(x, 0.f) + log1pf(__expf(-fabsf(x)));
}

// =============== K1a: EMA phase-1 (local chunk scans, zero init) ===============
__global__ __launch_bounds__(256) void ema_phase1(const float* __restrict__ x,
                                                  float* __restrict__ me, float* __restrict__ ve) {
    int tid = blockIdx.x * blockDim.x + threadIdx.x;
    if (tid >= NCE_ * B_ * F_) return;
    int c = tid / (B_ * F_);
    int r = tid % (B_ * F_);
    int b = r / F_, f = r % F_;
    const float al[L_] = {0.5f, 0.25f, 0.125f, 0.0625f};
    float m[L_] = {0,0,0,0}, v[L_] = {0,0,0,0};
    int t0 = c * CHE_;
    for (int i = 0; i < CHE_; ++i) {
        float xv = x[((t0 + i) * B_ + b) * F_ + f];
        #pragma unroll
        for (int l = 0; l < L_; ++l) {
            m[l] = al[l] * xv      + (1.f - al[l]) * m[l];
            v[l] = al[l] * xv * xv + (1.f - al[l]) * v[l];
        }
    }
    int o = ((c * B_ + b) * F_ + f) * L_;
    #pragma unroll
    for (int l = 0; l < L_; ++l) { me[o + l] = m[l]; ve[o + l] = v[l]; }
}

// =============== K1b: EMA chunk combine (sequential over chunks) ===============
__global__ __launch_bounds__(256) void ema_combine(const float* __restrict__ me, const float* __restrict__ ve,
                                                   float* __restrict__ ms, float* __restrict__ vs) {
    int tid = blockIdx.x * blockDim.x + threadIdx.x;
    if (tid >= B_ * F_ * L_) return;
    int l = tid % L_;
    int f = (tid / L_) % F_;
    int b = tid / (L_ * F_);
    const float al[L_] = {0.5f, 0.25f, 0.125f, 0.0625f};
    float dec = powf(1.f - al[l], (float)CHE_);
    float m = 0.f, v = 0.f;
    for (int c = 0; c < NCE_; ++c) {
        int o = ((c * B_ + b) * F_ + f) * L_ + l;
        ms[o] = m; vs[o] = v;
        m = dec * m + me[o];
        v = dec * v + ve[o];
    }
}

// =============== K1c: EMA phase-3 (recompute with true starts, write xe) ===============
__global__ __launch_bounds__(256) void ema_phase3(const float* __restrict__ x,
                                                  const float* __restrict__ ms, const float* __restrict__ vs,
                                                  float* __restrict__ xe) {
    int tid = blockIdx.x * blockDim.x + threadIdx.x;
    if (tid >= NCE_ * B_ * F_) return;
    int c = tid / (B_ * F_);
    int r = tid % (B_ * F_);
    int b = r / F_, f = r % F_;
    const float al[L_] = {0.5f, 0.25f, 0.125f, 0.0625f};
    float m[L_], v[L_];
    int o = ((c * B_ + b) * F_ + f) * L_;
    #pragma unroll
    for (int l = 0; l < L_; ++l) { m[l] = ms[o + l]; v[l] = vs[o + l]; }
    int t0 = c * CHE_;
    for (int i = 0; i < CHE_; ++i) {
        int t = t0 + i;
        float xv = x[(t * B_ + b) * F_ + f];
        float4 ov;
        float* op = (float*)&ov;
        #pragma unroll
        for (int l = 0; l < L_; ++l) {
            m[l] = al[l] * xv      + (1.f - al[l]) * m[l];
            v[l] = al[l] * xv * xv + (1.f - al[l]) * v[l];
            float var = fmaxf(v[l] - m[l] * m[l], 0.f);
            op[l] = (xv - m[l]) * rsqrtf(var + EPS_);
        }
        *(float4*)&xe[((size_t)t * B_ + b) * 12 + f * 4] = ov;
    }
}

// =============== K2: fused mid pipeline + SSM phase-1 ===============
// One block per (chunk c, batch b). 256 threads.
__global__ __launch_bounds__(256) void fused_mid(
    const float* __restrict__ xe_g, const float* __restrict__ W_in, const float* __restrict__ b_in,
    const float* __restrict__ rms_scale, const float* __restrict__ mW_in, const float* __restrict__ mb_in,
    const float* __restrict__ convW, const float* __restrict__ convb, const float* __restrict__ W_xp,
    const float* __restrict__ W_dt, const float* __restrict__ b_dt, const float* __restrict__ A_log,
    float* __restrict__ h_g, float* __restrict__ xc_g, float* __restrict__ sres_g, float* __restrict__ xp_g,
    float* __restrict__ hend_g, float* __restrict__ sumd_g)
{
    int blk = blockIdx.x;
    int c = blk / B_, b = blk % B_;
    int j = threadIdx.x;

    __shared__ __align__(16) float s_Win[12 * 64];
    __shared__ __align__(16) float s_bin[64];
    __shared__ __align__(16) float s_scale[64];
    __shared__ __align__(16) float s_mb[256];
    __shared__ __align__(16) float s_convW[DI_ * KC_];
    __shared__ __align__(16) float s_convb[DI_];
    __shared__ __align__(16) float s_Wxp[DI_ * NXP_];
    __shared__ __align__(16) float s_Wdt[DTR_ * DI_];
    __shared__ __align__(16) float s_bdt[DI_];
    __shared__ __align__(16) float s_xe[(CH_ + 3) * 12];
    __shared__ __align__(16) float s_hn[64];
    __shared__ __align__(16) float s_ring[4][DI_];
    __shared__ __align__(16) float s_xcb[DI_];
    __shared__ __align__(16) float s_xpb[NXP_];

    for (int i = j; i < 12 * 64; i += 256) s_Win[i] = W_in[i];
    for (int i = j; i < 64; i += 256) { s_bin[i] = b_in[i]; s_scale[i] = rms_scale[i]; }
    for (int i = j; i < 256; i += 256) s_mb[i] = mb_in[i];
    for (int i = j; i < DI_ * KC_; i += 256) s_convW[i] = convW[i];
    for (int i = j; i < DI_; i += 256) { s_convb[i] = convb[i]; s_bdt[i] = b_dt[i]; }
    for (int i = j; i < DI_ * NXP_; i += 256) s_Wxp[i] = W_xp[i];
    for (int i = j; i < DTR_ * DI_; i += 256) s_Wdt[i] = W_dt[i];
    if (j < DI_) {
        #pragma unroll
        for (int s = 0; s < 4; ++s) s_ring[s][j] = 0.f;
    }
    int t0 = c * CH_ - 3;
    for (int i = j; i < (CH_ + 3) * 12; i += 256) {
        int tt = t0 + i / 12;
        int q = i % 12;
        s_xe[i] = (tt >= 0) ? xe_g[((size_t)tt * B_ + b) * 12 + q] : 0.f;
    }

    // mW_in column j in registers
    float wc[64];
    #pragma unroll
    for (int k = 0; k < 64; ++k) wc[k] = mW_in[k * 256 + j];

    float Ar[DS_], hs[DS_];
    float sumd = 0.f;
    if (j < DI_) {
        #pragma unroll
        for (int s = 0; s < DS_; ++s) { Ar[s] = -__expf(A_log[j * DS_ + s]); hs[s] = 0.f; }
    }
    __syncthreads();

    for (int it = 0; it < CH_ + 3; ++it) {
        int t = t0 + it;
        if (t < 0) continue;            // uniform across block (only c==0)
        bool halo = (it < 3);

        if (j < 64) {
            float hk = s_bin[j];
            #pragma unroll
            for (int i = 0; i < 12; ++i) hk += s_xe[it * 12 + i] * s_Win[i * 64 + j];
            float ss = hk * hk;
            #pragma unroll
            for (int off = 32; off; off >>= 1) ss += __shfl_xor(ss, off);
            float rs = rsqrtf(ss * (1.f / 64.f) + EPS_);
            s_hn[j] = hk * rs * s_scale[j];
            if (!halo) h_g[((size_t)t * B_ + b) * 64 + j] = hk;
        }
        __syncthreads();

        // u = hn @ mW_in + mb   (weights in regs, hn broadcast from LDS)
        float u = s_mb[j];
        const float4* hn4 = (const float4*)s_hn;
        #pragma unroll
        for (int q = 0; q < 16; ++q) {
            float4 hh = hn4[q];
            u += hh.x * wc[4 * q] + hh.y * wc[4 * q + 1] + hh.z * wc[4 * q + 2] + hh.w * wc[4 * q + 3];
        }
        if (j < DI_) {
            s_ring[t & 3][j] = u;
        } else {
            float sr = u * sigmoidf_(u);
            if (!halo) sres_g[((size_t)t * B_ + b) * DI_ + (j - DI_)] = sr;
        }
        __syncthreads();
        if (halo) continue;

        if (j < DI_) {
            float xcv = s_convb[j];
            #pragma unroll
            for (int k = 0; k < KC_; ++k) xcv += s_convW[j * KC_ + k] * s_ring[(t + k + 1) & 3][j];
            float sx = xcv * sigmoidf_(xcv);
            xc_g[((size_t)t * B_ + b) * DI_ + j] = sx;
            s_xcb[j] = sx;
        }
        __syncthreads();

        // xp = xc @ W_xp  (36 outputs, 4 partial lanes each)
        if (j < 144) {
            int o = j >> 2, p = j & 3;
            float acc = 0.f;
            int d0 = p * 32;
            #pragma unroll 8
            for (int d = d0; d < d0 + 32; ++d) acc += s_xcb[d] * s_Wxp[d * NXP_ + o];
            acc += __shfl_xor(acc, 1);
            acc += __shfl_xor(acc, 2);
            if (p == 0) {
                s_xpb[o] = acc;
                xp_g[((size_t)t * B_ + b) * NXP_ + o] = acc;
            }
        }
        __syncthreads();

        // SSM phase-1: per-channel state update
        if (j < DI_) {
            float z = s_bdt[j];
            #pragma unroll
            for (int i = 0; i < DTR_; ++i) z += s_xpb[i] * s_Wdt[i * DI_ + j];
            float dl = softplusf_(z);
            sumd += dl;
            float dx = dl * s_xcb[j];
            #pragma unroll
            for (int s = 0; s < DS_; ++s) {
                float dA = __expf(dl * Ar[s]);
                hs[s] = dA * hs[s] + dx * s_xpb[4 + s];
            }
        }
        // next iteration's LDS writes are ordered by the two barriers at its top
    }

    if (j < DI_) {
        size_t o = (size_t)(c * B_ + b) * DI_ + j;
        float4* he4 = (float4*)&hend_g[o * DS_];
        #pragma unroll
        for (int q = 0; q < 4; ++q) {
            float4 hv = make_float4(hs[4*q], hs[4*q+1], hs[4*q+2], hs[4*q+3]);
            he4[q] = hv;
        }
        sumd_g[o] = sumd;
    }
}

// =============== K3: SSM chunk combine ===============
__global__ __launch_bounds__(256) void ssm_combine(const float* __restrict__ A_log,
                                                   const float* __restrict__ hend, const float* __restrict__ sumd,
                                                   float* __restrict__ hstart) {
    int tid = blockIdx.x * blockDim.x + threadIdx.x;   // B*DI*DS = 65536
    int s = tid & (DS_ - 1);
    int d = (tid >> 4) & (DI_ - 1);
    int b = tid >> 11;
    float A = -__expf(A_log[d * DS_ + s]);
    float h = 0.f;
    for (int c = 0; c < NC_; ++c) {
        size_t o = (size_t)(c * B_ + b) * DI_ + d;
        hstart[o * DS_ + s] = h;
        h = __expf(A * sumd[o]) * h + hend[o * DS_ + s];
    }
}

// =============== K4: SSM phase-3 + epilogue (W_out, residual, W_sim) ===============
__global__ __launch_bounds__(128) void ssm_phase3_out(
    const float* __restrict__ xp_g, const float* __restrict__ xc_g, const float* __restrict__ sres_g,
    const float* __restrict__ h_g, const float* __restrict__ hstart, const float* __restrict__ A_log,
    const float* __restrict__ W_dt, const float* __restrict__ b_dt, const float* __restrict__ Dp,
    const float* __restrict__ W_out, const float* __restrict__ b_out,
    const float* __restrict__ W_sim, const float* __restrict__ b_sim, float* __restrict__ out)
{
    int blk = blockIdx.x;
    int c = blk / B_, b = blk % B_;
    int j = threadIdx.x;

    __shared__ __align__(16) float s_Wout[DI_ * D_];   // 32 KB
    __shared__ __align__(16) float s_Wdt[DTR_ * DI_];
    __shared__ __align__(16) float s_bdt[DI_];
    __shared__ __align__(16) float s_Wsim[D_ * 3];
    __shared__ __align__(16) float s_xp[NXP_];
    __shared__ __align__(16) float s_y[DI_];
    __shared__ __align__(16) float s_pb[DI_];

    for (int i = j; i < DI_ * D_; i += 128) s_Wout[i] = W_out[i];
    for (int i = j; i < DTR_ * DI_; i += 128) s_Wdt[i] = W_dt[i];
    for (int i = j; i < DI_; i += 128) s_bdt[i] = b_dt[i];
    for (int i = j; i < D_ * 3; i += 128) s_Wsim[i] = W_sim[i];
    float bs0 = b_sim[0], bs1 = b_sim[1], bs2 = b_sim[2];

    float Ar[DS_], hs[DS_];
    float dp = Dp[j];
    {
        #pragma unroll
        for (int s = 0; s < DS_; ++s) Ar[s] = -__expf(A_log[j * DS_ + s]);
        const float4* h4 = (const float4*)&hstart[((size_t)(c * B_ + b) * DI_ + j) * DS_];
        #pragma unroll
        for (int q = 0; q < 4; ++q) {
            float4 hv = h4[q];
            hs[4*q] = hv.x; hs[4*q+1] = hv.y; hs[4*q+2] = hv.z; hs[4*q+3] = hv.w;
        }
    }
    float bo = (j < 64) ? b_out[j] : 0.f;
    __syncthreads();

    int t0 = c * CH_;
    for (int it = 0; it < CH_; ++it) {
        int t = t0 + it;
        size_t base = (size_t)t * B_ + b;
        float xcv = xc_g[base * DI_ + j];
        float srv = sres_g[base * DI_ + j];
        if (j < NXP_) s_xp[j] = xp_g[base * NXP_ + j];
        __syncthreads();

        float z = s_bdt[j];
        #pragma unroll
        for (int i = 0; i < DTR_; ++i) z += s_xp[i] * s_Wdt[i * DI_ + j];
        float dl = softplusf_(z);
        float dx = dl * xcv;
        float y = 0.f;
        #pragma unroll
        for (int s = 0; s < DS_; ++s) {
            float dA = __expf(dl * Ar[s]);
            hs[s] = dA * hs[s] + dx * s_xp[4 + s];
            y += hs[s] * s_xp[20 + s];
        }
        y = (y + dp * xcv) * srv;
        s_y[j] = y;
        __syncthreads();

        {   // W_out GEMV split over 2 halves of d
            int col = j & 63, half = j >> 6;
            float p = 0.f;
            const float* yb = s_y + half * 64;
            const float* wb = s_Wout + half * 64 * D_;
            #pragma unroll 8
            for (int d = 0; d < 64; ++d) p += yb[d] * wb[d * D_ + col];
            s_pb[j] = p;
        }
        __syncthreads();

        if (j < 64) {
            float f = s_pb[j] + s_pb[j + 64] + bo + h_g[base * D_ + j];
            float r0 = f * s_Wsim[j * 3 + 0];
            float r1 = f * s_Wsim[j * 3 + 1];
            float r2 = f * s_Wsim[j * 3 + 2];
            #pragma unroll
            for (int off = 32; off; off >>= 1) {
                r0 += __shfl_xor(r0, off);
                r1 += __shfl_xor(r1, off);
                r2 += __shfl_xor(r2, off);
            }
            if (j == 0) {
                out[base * 3 + 0] = r0 + bs0;
                out[base * 3 + 1] = r1 + bs1;
                out[base * 3 + 2] = r2 + bs2;
            }
        }
        // barriers at next-iteration top order the s_xp/s_y/s_pb rewrites
    }
}

// =============== launch ===============
extern "C" void kernel_launch(void* const* d_in, const int* in_sizes, int n_in,
                              void* d_out, int out_size, void* d_ws, size_t ws_size,
                              hipStream_t stream) {
    const float* x         = (const float*)d_in[0];
    const float* W_in      = (const float*)d_in[1];
    const float* b_in      = (const float*)d_in[2];
    const float* rms_scale = (const float*)d_in[3];
    const float* mW_in     = (const float*)d_in[4];
    const float* mb_in     = (const float*)d_in[5];
    const float* convW     = (const float*)d_in[6];
    const float* convb     = (const float*)d_in[7];
    const float* W_xp      = (const float*)d_in[8];
    const float* W_dt      = (const float*)d_in[9];
    const float* b_dt      = (const float*)d_in[10];
    const float* A_log     = (const float*)d_in[11];
    const float* Dp        = (const float*)d_in[12];
    const float* W_out     = (const float*)d_in[13];
    const float* b_out     = (const float*)d_in[14];
    const float* W_sim     = (const float*)d_in[15];
    const float* b_sim     = (const float*)d_in[16];
    float* out = (float*)d_out;
    float* ws  = (float*)d_ws;

    float* xe    = ws + XE_OFF;
    float* h_g   = ws + H_OFF;
    float* xc_g  = ws + XC_OFF;
    float* sres  = ws + SRES_OFF;
    float* xp_g  = ws + XP_OFF;
    float* hend  = ws + HEND_OFF;
    float* sumd  = ws + SUMD_OFF;
    float* hstart= ws + HST_OFF;
    float* eme   = ws + EME_OFF;
    float* eve   = ws + EVE_OFF;
    float* ems   = ws + EMS_OFF;
    float* evs   = ws + EVS_OFF;

    ema_phase1<<<(NCE_*B_*F_ + 255)/256, 256, 0, stream>>>(x, eme, eve);
    ema_combine<<<(B_*F_*L_ + 255)/256, 256, 0, stream>>>(eme, eve, ems, evs);
    ema_phase3<<<(NCE_*B_*F_ + 255)/256, 256, 0, stream>>>(x, ems, evs, xe);
    fused_mid<<<NC_*B_, 256, 0, stream>>>(xe, W_in, b_in, rms_scale, mW_in, mb_in,
                                          convW, convb, W_xp, W_dt, b_dt, A_log,
                                          h_g, xc_g, sres, xp_g, hend, sumd);
    ssm_combine<<<(B_*DI_*DS_)/256, 256, 0, stream>>>(A_log, hend, sumd, hstart);
    ssm_phase3_out<<<NC_*B_, 128, 0, stream>>>(xp_g, xc_g, sres, h_g, hstart, A_log,
                                               W_dt, b_dt, Dp, W_out, b_out,
                                               W_sim, b_sim, out);
}

// Round 3
// 681.023 us; speedup vs baseline: 1.5352x; 1.5352x over previous
//
#include <hip/hip_runtime.h>
#include <hip/hip_bf16.h>
#include <math.h>

#define T_    4096
#define B_    32
#define F_    3
#define L_    4
#define D_    64
#define DI_   128
#define DS_   16
#define DTR_  4
#define KC_   4
#define NXP_  36
#define EPS_  1e-6f

#define CH_   128
#define NC_   (T_/CH_)        // 32 chunks
#define CHE_  64
#define NCE_  (T_/CHE_)

// ---------------- workspace layout (float offsets), total ~52.66M floats = 210.6 MB ----------------
#define XE_OFF    ((size_t)0)                           // T*B*12
#define H_OFF     (XE_OFF   + (size_t)T_*B_*12)         // T*B*64
#define XM_OFF    (H_OFF    + (size_t)T_*B_*64)         // T*B*128 (pre-conv xm)
#define SRES_OFF  (XM_OFF   + (size_t)T_*B_*128)        // T*B*128 (silu(res); overwritten in-place by gated y)
#define XP_OFF    (SRES_OFF + (size_t)T_*B_*128)        // T*B*36
#define HEND_OFF  (XP_OFF   + (size_t)T_*B_*36)         // NC*B*DS*DI  layout [(c,b)][s][d]
#define SUMD_OFF  (HEND_OFF + (size_t)NC_*B_*DI_*DS_)   // NC*B*DI
#define HST_OFF   (SUMD_OFF + (size_t)NC_*B_*DI_)       // NC*B*DS*DI
#define EME_OFF   (HST_OFF  + (size_t)NC_*B_*DI_*DS_)
#define EVE_OFF   (EME_OFF  + (size_t)NCE_*B_*F_*L_)
#define EMS_OFF   (EVE_OFF  + (size_t)NCE_*B_*F_*L_)
#define EVS_OFF   (EMS_OFF  + (size_t)NCE_*B_*F_*L_)
#define FOLD_OFF  (EVS_OFF  + (size_t)NCE_*B_*F_*L_)    // 384 Wc + 3 bsc

__device__ __forceinline__ float sigmoidf_(float x) { return 1.f / (1.f + __expf(-x)); }
__device__ __forceinline__ float softplusf_(float x) {
    return fmaxf(x, 0.f) + log1pf(__expf(-fabsf(x)));
}

// =============== EMA (3-phase chunked scan) — unchanged, proven in R0 ===============
__global__ __launch_bounds__(256) void ema_phase1(const float* __restrict__ x,
                                                  float* __restrict__ me, float* __restrict__ ve) {
    int tid = blockIdx.x * blockDim.x + threadIdx.x;
    if (tid >= NCE_ * B_ * F_) return;
    int c = tid / (B_ * F_);
    int r = tid % (B_ * F_);
    int b = r / F_, f = r % F_;
    const float al[L_] = {0.5f, 0.25f, 0.125f, 0.0625f};
    float m[L_] = {0,0,0,0}, v[L_] = {0,0,0,0};
    int t0 = c * CHE_;
    for (int i = 0; i < CHE_; ++i) {
        float xv = x[((t0 + i) * B_ + b) * F_ + f];
        #pragma unroll
        for (int l = 0; l < L_; ++l) {
            m[l] = al[l] * xv      + (1.f - al[l]) * m[l];
            v[l] = al[l] * xv * xv + (1.f - al[l]) * v[l];
        }
    }
    int o = ((c * B_ + b) * F_ + f) * L_;
    #pragma unroll
    for (int l = 0; l < L_; ++l) { me[o + l] = m[l]; ve[o + l] = v[l]; }
}

__global__ __launch_bounds__(256) void ema_combine(const float* __restrict__ me, const float* __restrict__ ve,
                                                   float* __restrict__ ms, float* __restrict__ vs) {
    int tid = blockIdx.x * blockDim.x + threadIdx.x;
    if (tid >= B_ * F_ * L_) return;
    int l = tid % L_;
    int f = (tid / L_) % F_;
    int b = tid / (L_ * F_);
    const float al[L_] = {0.5f, 0.25f, 0.125f, 0.0625f};
    float dec = powf(1.f - al[l], (float)CHE_);
    float m = 0.f, v = 0.f;
    for (int c = 0; c < NCE_; ++c) {
        int o = ((c * B_ + b) * F_ + f) * L_ + l;
        ms[o] = m; vs[o] = v;
        m = dec * m + me[o];
        v = dec * v + ve[o];
    }
}

__global__ __launch_bounds__(256) void ema_phase3(const float* __restrict__ x,
                                                  const float* __restrict__ ms, const float* __restrict__ vs,
                                                  float* __restrict__ xe) {
    int tid = blockIdx.x * blockDim.x + threadIdx.x;
    if (tid >= NCE_ * B_ * F_) return;
    int c = tid / (B_ * F_);
    int r = tid % (B_ * F_);
    int b = r / F_, f = r % F_;
    const float al[L_] = {0.5f, 0.25f, 0.125f, 0.0625f};
    float m[L_], v[L_];
    int o = ((c * B_ + b) * F_ + f) * L_;
    #pragma unroll
    for (int l = 0; l < L_; ++l) { m[l] = ms[o + l]; v[l] = vs[o + l]; }
    int t0 = c * CHE_;
    for (int i = 0; i < CHE_; ++i) {
        int t = t0 + i;
        float xv = x[(t * B_ + b) * F_ + f];
        float4 ov;
        float* op = (float*)&ov;
        #pragma unroll
        for (int l = 0; l < L_; ++l) {
            m[l] = al[l] * xv      + (1.f - al[l]) * m[l];
            v[l] = al[l] * xv * xv + (1.f - al[l]) * v[l];
            float var = fmaxf(v[l] - m[l] * m[l], 0.f);
            op[l] = (xv - m[l]) * rsqrtf(var + EPS_);
        }
        *(float4*)&xe[((size_t)t * B_ + b) * 12 + f * 4] = ov;
    }
}

// =============== K_A: h + rmsnorm + u GEMM (64 rows/block) ===============
__global__ __launch_bounds__(256) void gemm_in(
    const float* __restrict__ xe_g, const float* __restrict__ W_in, const float* __restrict__ b_in,
    const float* __restrict__ rms_scale, const float* __restrict__ mW_in, const float* __restrict__ mb_in,
    float* __restrict__ h_g, float* __restrict__ xm_g, float* __restrict__ sres_g)
{
    __shared__ __align__(16) float s_xe[64 * 12];
    __shared__ __align__(16) float s_hn[64 * 64];
    __shared__ __align__(16) float s_Win[12 * 64];
    int tid = threadIdx.x;
    size_t g0 = (size_t)blockIdx.x * 64;

    for (int i = tid; i < 12 * 64; i += 256) s_Win[i] = W_in[i];
    for (int i = tid; i < 64 * 12; i += 256) s_xe[i] = xe_g[g0 * 12 + i];
    __syncthreads();

    int lane = tid & 63, w = tid >> 6;
    float bin = b_in[lane], scl = rms_scale[lane];
    #pragma unroll 4
    for (int i = 0; i < 16; ++i) {
        int r = w * 16 + i;
        float hv = bin;
        #pragma unroll
        for (int k = 0; k < 12; ++k) hv += s_xe[r * 12 + k] * s_Win[k * 64 + lane];
        h_g[(g0 + r) * 64 + lane] = hv;
        float ss = hv * hv;
        #pragma unroll
        for (int off = 32; off; off >>= 1) ss += __shfl_xor(ss, off);
        s_hn[r * 64 + lane] = hv * rsqrtf(ss * (1.f / 64.f) + EPS_) * scl;
    }

    float wc[64];
    #pragma unroll
    for (int k = 0; k < 64; ++k) wc[k] = mW_in[k * 256 + tid];
    float mb = mb_in[tid];
    __syncthreads();

    bool isres = tid >= 128;
    float* outp = isres ? (sres_g + g0 * 128 + (tid - 128)) : (xm_g + g0 * 128 + tid);
    for (int r = 0; r < 64; ++r) {
        float u = mb;
        const float4* hn4 = (const float4*)(s_hn + r * 64);
        #pragma unroll
        for (int q = 0; q < 16; ++q) {
            float4 hh = hn4[q];
            u += hh.x * wc[4*q] + hh.y * wc[4*q+1] + hh.z * wc[4*q+2] + hh.w * wc[4*q+3];
        }
        if (isres) u = u * sigmoidf_(u);
        outp[(size_t)r * 128] = u;
    }
}

// =============== K_B: conv + silu + xp GEMM (block = one t, all 32 b); xp only ===============
#define XCPAD 132
__global__ __launch_bounds__(256) void conv_xp(
    const float* __restrict__ xm_g, const float* __restrict__ convW, const float* __restrict__ convb,
    const float* __restrict__ W_xp, float* __restrict__ xp_g)
{
    int t = blockIdx.x;
    int tid = threadIdx.x;
    __shared__ __align__(16) float s_xc[32 * XCPAD];
    __shared__ __align__(16) float s_Wxp[128 * 36];
    __shared__ __align__(16) float s_convWT[4 * 128];
    __shared__ __align__(16) float s_convb[128];

    for (int i = tid; i < 128 * 36; i += 256) s_Wxp[i] = W_xp[i];
    for (int i = tid; i < 512; i += 256) s_convWT[(i & 3) * 128 + (i >> 2)] = convW[i];
    if (tid < 128) s_convb[tid] = convb[tid];
    __syncthreads();

    #pragma unroll
    for (int i = tid; i < 4096; i += 256) {
        int b = i >> 7, j = i & 127;
        float acc = s_convb[j];
        #pragma unroll
        for (int k = 0; k < 4; ++k) {
            int tt = t - 3 + k;
            float xv = (tt >= 0) ? xm_g[((size_t)tt * 32 + b) * 128 + j] : 0.f;
            acc += s_convWT[k * 128 + j] * xv;
        }
        acc = acc * sigmoidf_(acc);
        s_xc[b * XCPAD + j] = acc;
    }
    __syncthreads();

    int b = tid >> 3, q = tid & 7;
    float acc[36];
    #pragma unroll
    for (int o = 0; o < 36; ++o) acc[o] = 0.f;
    #pragma unroll
    for (int dd = 0; dd < 16; ++dd) {
        int d = q + dd * 8;
        float xv = s_xc[b * XCPAD + d];
        const float* wr = s_Wxp + d * 36;
        #pragma unroll
        for (int o = 0; o < 36; ++o) acc[o] += xv * wr[o];
    }
    #pragma unroll
    for (int o = 0; o < 36; ++o) {
        acc[o] += __shfl_xor(acc[o], 1);
        acc[o] += __shfl_xor(acc[o], 2);
        acc[o] += __shfl_xor(acc[o], 4);
    }
    if (q == 0) {
        float* xpo = xp_g + ((size_t)t * 32 + b) * 36;
        #pragma unroll
        for (int o4 = 0; o4 < 9; ++o4)
            *(float4*)&xpo[o4 * 4] = make_float4(acc[o4*4], acc[o4*4+1], acc[o4*4+2], acc[o4*4+3]);
    }
}

// =============== P1: SSM local scan, barrier-free; xc recomputed from xm (sliding FIR) ===============
__global__ __launch_bounds__(128) void ssm_phase1(
    const float* __restrict__ xm_g, const float* __restrict__ xp_g,
    const float* __restrict__ convW, const float* __restrict__ convb,
    const float* __restrict__ W_dt, const float* __restrict__ b_dt, const float* __restrict__ A_log,
    float* __restrict__ hend_g, float* __restrict__ sumd_g)
{
    int c = blockIdx.x >> 5;
    int b = blockIdx.x & 31;
    int j = threadIdx.x;
    float Ar[16], hs[16];
    #pragma unroll
    for (int s = 0; s < 16; ++s) { Ar[s] = -__expf(A_log[j * 16 + s]); hs[s] = 0.f; }
    float wdt[4];
    #pragma unroll
    for (int i = 0; i < 4; ++i) wdt[i] = W_dt[i * 128 + j];
    float bdt = b_dt[j];
    float cw0 = convW[j*4+0], cw1 = convW[j*4+1], cw2 = convW[j*4+2], cw3 = convW[j*4+3];
    float cb = convb[j];
    int t0 = c * CH_;
    float x3 = 0.f, x2 = 0.f, x1 = 0.f;
    if (t0 >= 3) {
        x3 = xm_g[((size_t)(t0-3) * 32 + b) * 128 + j];
        x2 = xm_g[((size_t)(t0-2) * 32 + b) * 128 + j];
        x1 = xm_g[((size_t)(t0-1) * 32 + b) * 128 + j];
    }
    float sumd = 0.f;
    for (int it = 0; it < CH_; ++it) {
        size_t row = (size_t)(t0 + it) * 32 + b;
        float x0 = xm_g[row * 128 + j];
        float xc = cb + cw0 * x3 + cw1 * x2 + cw2 * x1 + cw3 * x0;
        x3 = x2; x2 = x1; x1 = x0;
        xc = xc * sigmoidf_(xc);
        const float4* xp4 = (const float4*)(xp_g + row * 36);
        float4 dt4 = xp4[0];
        float z = bdt + dt4.x * wdt[0] + dt4.y * wdt[1] + dt4.z * wdt[2] + dt4.w * wdt[3];
        float dl = softplusf_(z);
        sumd += dl;
        float dx = dl * xc;
        #pragma unroll
        for (int qq = 0; qq < 4; ++qq) {
            float4 Bm = xp4[1 + qq];
            float* bp = (float*)&Bm;
            #pragma unroll
            for (int u = 0; u < 4; ++u) {
                int s = qq * 4 + u;
                hs[s] = __expf(dl * Ar[s]) * hs[s] + dx * bp[u];
            }
        }
    }
    size_t cbk = (size_t)blockIdx.x;
    #pragma unroll
    for (int s = 0; s < 16; ++s) hend_g[(cbk * 16 + s) * 128 + j] = hs[s];
    sumd_g[cbk * 128 + j] = sumd;
}

// =============== K3: SSM chunk combine ===============
__global__ __launch_bounds__(256) void ssm_combine(
    const float* __restrict__ A_log, const float* __restrict__ hend,
    const float* __restrict__ sumd, float* __restrict__ hstart)
{
    int tid = blockIdx.x * 256 + threadIdx.x;   // (b,s,d): B*DS*DI = 65536
    int d = tid & 127;
    int s = (tid >> 7) & 15;
    int b = tid >> 11;
    float A = -__expf(A_log[d * 16 + s]);
    float h = 0.f;
    for (int c = 0; c < NC_; ++c) {
        size_t cb = (size_t)(c * 32 + b);
        hstart[(cb * 16 + s) * 128 + d] = h;
        h = __expf(A * sumd[cb * 128 + d]) * h + hend[(cb * 16 + s) * 128 + d];
    }
}

// =============== P3: rescan with true starts; gated y overwrites sres in-place ===============
__global__ __launch_bounds__(128) void ssm_phase3(
    const float* __restrict__ xm_g, const float* __restrict__ xp_g, float* sres_y,
    const float* __restrict__ hstart, const float* __restrict__ convW, const float* __restrict__ convb,
    const float* __restrict__ W_dt, const float* __restrict__ b_dt, const float* __restrict__ A_log,
    const float* __restrict__ Dp)
{
    int c = blockIdx.x >> 5;
    int b = blockIdx.x & 31;
    int j = threadIdx.x;
    size_t cbk = (size_t)blockIdx.x;
    float Ar[16], hs[16];
    #pragma unroll
    for (int s = 0; s < 16; ++s) {
        Ar[s] = -__expf(A_log[j * 16 + s]);
        hs[s] = hstart[(cbk * 16 + s) * 128 + j];
    }
    float wdt[4];
    #pragma unroll
    for (int i = 0; i < 4; ++i) wdt[i] = W_dt[i * 128 + j];
    float bdt = b_dt[j];
    float cw0 = convW[j*4+0], cw1 = convW[j*4+1], cw2 = convW[j*4+2], cw3 = convW[j*4+3];
    float cb = convb[j];
    float dp = Dp[j];
    int t0 = c * CH_;
    float x3 = 0.f, x2 = 0.f, x1 = 0.f;
    if (t0 >= 3) {
        x3 = xm_g[((size_t)(t0-3) * 32 + b) * 128 + j];
        x2 = xm_g[((size_t)(t0-2) * 32 + b) * 128 + j];
        x1 = xm_g[((size_t)(t0-1) * 32 + b) * 128 + j];
    }
    for (int it = 0; it < CH_; ++it) {
        size_t row = (size_t)(t0 + it) * 32 + b;
        float x0 = xm_g[row * 128 + j];
        float xc = cb + cw0 * x3 + cw1 * x2 + cw2 * x1 + cw3 * x0;
        x3 = x2; x2 = x1; x1 = x0;
        xc = xc * sigmoidf_(xc);
        const float4* xp4 = (const float4*)(xp_g + row * 36);
        float4 dt4 = xp4[0];
        float z = bdt + dt4.x * wdt[0] + dt4.y * wdt[1] + dt4.z * wdt[2] + dt4.w * wdt[3];
        float dl = softplusf_(z);
        float dx = dl * xc;
        float y = 0.f;
        #pragma unroll
        for (int qq = 0; qq < 4; ++qq) {
            float4 Bm = xp4[1 + qq];
            float4 Cm = xp4[5 + qq];
            float* bp = (float*)&Bm;
            float* cp = (float*)&Cm;
            #pragma unroll
            for (int u = 0; u < 4; ++u) {
                int s = qq * 4 + u;
                hs[s] = __expf(dl * Ar[s]) * hs[s] + dx * bp[u];
                y += hs[s] * cp[u];
            }
        }
        float sr = sres_y[row * 128 + j];
        sres_y[row * 128 + j] = (y + dp * xc) * sr;   // in-place: gated y
    }
}

// =============== fold_w: Wc = W_out @ W_sim (128x3), bsc = b_out @ W_sim + b_sim ===============
__global__ __launch_bounds__(256) void fold_w(
    const float* __restrict__ W_out, const float* __restrict__ b_out,
    const float* __restrict__ W_sim, const float* __restrict__ b_sim, float* __restrict__ fold)
{
    int tid = threadIdx.x;
    for (int i = tid; i < 384; i += 256) {
        int d = i / 3, o = i % 3;
        float a = 0.f;
        for (int k = 0; k < 64; ++k) a += W_out[d * 64 + k] * W_sim[k * 3 + o];
        fold[i] = a;
    }
    if (tid < 3) {
        float a = b_sim[tid];
        for (int k = 0; k < 64; ++k) a += b_out[k] * W_sim[k * 3 + tid];
        fold[384 + tid] = a;
    }
}

// =============== out_gemm: out = y@Wc + h@W_sim + bsc (wave per row) ===============
__global__ __launch_bounds__(256) void out_gemm(
    const float* __restrict__ y_g, const float* __restrict__ h_g,
    const float* __restrict__ W_sim, const float* __restrict__ fold, float* __restrict__ out)
{
    __shared__ __align__(16) float s_Wc[384];
    __shared__ __align__(16) float s_Ws[192];
    __shared__ float s_bsc[3];
    int tid = threadIdx.x;
    for (int i = tid; i < 384; i += 256) s_Wc[i] = fold[i];
    for (int i = tid; i < 192; i += 256) s_Ws[i] = W_sim[i];
    if (tid < 3) s_bsc[tid] = fold[384 + tid];
    __syncthreads();

    int lane = tid & 63, wid = tid >> 6;
    size_t row0 = (size_t)blockIdx.x * 128;
    for (int it = 0; it < 32; ++it) {
        size_t row = row0 + it * 4 + wid;
        const float* yr = y_g + row * 128;
        float y1 = yr[lane], y2 = yr[64 + lane];
        float hv = h_g[row * 64 + lane];
        float p0 = y1 * s_Wc[lane*3+0] + y2 * s_Wc[(64+lane)*3+0] + hv * s_Ws[lane*3+0];
        float p1 = y1 * s_Wc[lane*3+1] + y2 * s_Wc[(64+lane)*3+1] + hv * s_Ws[lane*3+1];
        float p2 = y1 * s_Wc[lane*3+2] + y2 * s_Wc[(64+lane)*3+2] + hv * s_Ws[lane*3+2];
        #pragma unroll
        for (int off = 32; off; off >>= 1) {
            p0 += __shfl_xor(p0, off);
            p1 += __shfl_xor(p1, off);
            p2 += __shfl_xor(p2, off);
        }
        if (lane == 0) {
            out[row * 3 + 0] = p0 + s_bsc[0];
            out[row * 3 + 1] = p1 + s_bsc[1];
            out[row * 3 + 2] = p2 + s_bsc[2];
        }
    }
}

// =============== launch ===============
extern "C" void kernel_launch(void* const* d_in, const int* in_sizes, int n_in,
                              void* d_out, int out_size, void* d_ws, size_t ws_size,
                              hipStream_t stream) {
    const float* x         = (const float*)d_in[0];
    const float* W_in      = (const float*)d_in[1];
    const float* b_in      = (const float*)d_in[2];
    const float* rms_scale = (const float*)d_in[3];
    const float* mW_in     = (const float*)d_in[4];
    const float* mb_in     = (const float*)d_in[5];
    const float* convW     = (const float*)d_in[6];
    const float* convb     = (const float*)d_in[7];
    const float* W_xp      = (const float*)d_in[8];
    const float* W_dt      = (const float*)d_in[9];
    const float* b_dt      = (const float*)d_in[10];
    const float* A_log     = (const float*)d_in[11];
    const float* Dp        = (const float*)d_in[12];
    const float* W_out     = (const float*)d_in[13];
    const float* b_out     = (const float*)d_in[14];
    const float* W_sim     = (const float*)d_in[15];
    const float* b_sim     = (const float*)d_in[16];
    float* out = (float*)d_out;
    float* ws  = (float*)d_ws;

    float* xe    = ws + XE_OFF;
    float* h_g   = ws + H_OFF;
    float* xm_g  = ws + XM_OFF;
    float* sres  = ws + SRES_OFF;    // becomes gated y after ssm_phase3
    float* xp_g  = ws + XP_OFF;
    float* hend  = ws + HEND_OFF;
    float* sumd  = ws + SUMD_OFF;
    float* hstart= ws + HST_OFF;
    float* eme   = ws + EME_OFF;
    float* eve   = ws + EVE_OFF;
    float* ems   = ws + EMS_OFF;
    float* evs   = ws + EVS_OFF;
    float* fold  = ws + FOLD_OFF;

    ema_phase1<<<(NCE_*B_*F_ + 255)/256, 256, 0, stream>>>(x, eme, eve);
    ema_combine<<<(B_*F_*L_ + 255)/256, 256, 0, stream>>>(eme, eve, ems, evs);
    ema_phase3<<<(NCE_*B_*F_ + 255)/256, 256, 0, stream>>>(x, ems, evs, xe);
    fold_w<<<1, 256, 0, stream>>>(W_out, b_out, W_sim, b_sim, fold);
    gemm_in<<<T_*B_/64, 256, 0, stream>>>(xe, W_in, b_in, rms_scale, mW_in, mb_in,
                                          h_g, xm_g, sres);
    conv_xp<<<T_, 256, 0, stream>>>(xm_g, convW, convb, W_xp, xp_g);
    ssm_phase1<<<NC_*B_, 128, 0, stream>>>(xm_g, xp_g, convW, convb, W_dt, b_dt, A_log,
                                           hend, sumd);
    ssm_combine<<<(B_*DI_*DS_)/256, 256, 0, stream>>>(A_log, hend, sumd, hstart);
    ssm_phase3<<<NC_*B_, 128, 0, stream>>>(xm_g, xp_g, sres, hstart, convW, convb,
                                           W_dt, b_dt, A_log, Dp);
    out_gemm<<<T_*B_/128, 256, 0, stream>>>(sres, h_g, W_sim, fold, out);
}